// Round 11
// baseline (138.228 us; speedup 1.0000x reference)
//
#include <hip/hip_runtime.h>

// ScalarDistanceDeepSet: B=32, N=256, pairs P=32640 (upper tri, k=1)
// phi: s -> relu(s*W1+b1)[64] -> relu(.@W2+b2)[128], masked sum over pairs
// rho: pooled[128] -> 256 -> 128 -> 64
//
// g_e(s) is piecewise-linear in s with 64 shared breakpoints. Tables
// alpha/beta[seg][e] make per-(pair,channel) work 1 FMA + 1 max. EXACT.
//
// R17: R16 won (126.3). Remaining slack is structural in phi: (1) grid
// (16,32)=512 blocks == exact 2-blocks/CU residency -> NO refill when
// short blocks finish; (2) the wave owning row 0 of a len~255 batch does
// 254 serial visits alone. Fix both: grid (32,32)=1024 blocks (2 rounds
// -> refill), each block = 8 rows x 2 column-halves across 16 waves
// (wave pair splits a row's interior groups at the midpoint, edges with
// half 0). Longest wave chain 254 -> ~127 visits. Costs: 2x table
// staging + 2x row loads (cheap; visit count UNCHANGED, unlike R10's
// failed 4x parity split). Two partial sums per row via atomicAdd ->
// regrouped accumulation, absmax <= 0.0625 tolerated (R4/R12).
// build = R16 (no W2 staging), rho = R13 (no weight staging).

#define NB 32
#define NN 256
#define PHI2 128
#define SEGS 65

// ---------------- Kernel A: build tables (no W2 staging) ----------------
// grid: 65 blocks (one per segment), 128 threads (one per output channel e)
// table viewed as float4[seg][l] = (a_l, b_l, a_{l+64}, b_{l+64})
__global__ __launch_bounds__(128) void build_tables(
    const float* __restrict__ W1, const float* __restrict__ b1,
    const float* __restrict__ W2, const float* __restrict__ b2,
    float2* __restrict__ table2,   // float2[(seg*64+l)*2 + h]
    float* __restrict__ tsort, float* __restrict__ pooled) {
  __shared__ float t_s[64], w1_s[64], b1_s[64];
  __shared__ int cat_s[64], rank_s[64];
  const int tid = threadIdx.x;
  const int seg = blockIdx.x;
  if (tid < 64) {
    float w = W1[tid], bb = b1[tid];
    w1_s[tid] = w; b1_s[tid] = bb;
    int cat; float t;
    if (w > 0.f)      { cat = 0; t = -bb / w; }   // active for s > t
    else if (w < 0.f) { cat = 1; t = -bb / w; }   // active for s < t
    else              { cat = (bb > 0.f) ? 2 : 3; t = 0.f; } // always/never
    t_s[tid] = t; cat_s[tid] = cat;
  }
  __syncthreads();
  if (tid < 64) {
    float t = t_s[tid]; int r = 0;
    for (int k = 0; k < 64; ++k) {
      float tk = t_s[k];
      r += (tk < t) || (tk == t && k < tid);   // stable rank
    }
    rank_s[tid] = r;
    if (seg == 0) tsort[r] = t;
  }
  __syncthreads();
  // channel e = tid. seg(s) = #breakpoints strictly < s.
  // W2[j*PHI2+tid]: coalesced across tid, L2-hot, 8 loads in flight.
  float a = 0.f, bsum = b2[tid];
#pragma unroll 8
  for (int j = 0; j < 64; ++j) {
    int cat = cat_s[j], r = rank_s[j];
    bool act = (cat == 0) ? (seg > r) : (cat == 1) ? (seg <= r) : (cat == 2);
    float w2 = W2[j * PHI2 + tid];
    float m = act ? 1.f : 0.f;
    a    = fmaf(m * w1_s[j], w2, a);
    bsum = fmaf(m * b1_s[j], w2, bsum);
  }
  const int h = tid >> 6, l = tid & 63;
  table2[(seg * 64 + l) * 2 + h] = make_float2(a, bsum);
  if (seg == 0) {
    for (int i = tid; i < NB * PHI2; i += 128) pooled[i] = 0.f;
  }
}

__device__ __forceinline__ float bcast(float v, int L) {
  return __int_as_float(__builtin_amdgcn_readlane(__float_as_int(v), L));
}
__device__ __forceinline__ int segof(float tv, float s) {
  return (int)__popcll(__ballot(tv < s));
}

// One (pair) visit covering BOTH channel halves: broadcast s from lane L
// (uniform), segment via ballot over register-held breakpoints, one
// ds_read_b128 -> (a_lo,b_lo,a_hi,b_hi). 1 readlane/ballot per PAIR.
__device__ __forceinline__ void visit(float comp, int L, float tv, int lane,
                                      const float4* ab_s,
                                      float& a0, float& a1) {
  float s = bcast(comp, L);
  float4 p = ab_s[segof(tv, s) * 64 + lane];
  a0 += fmaxf(fmaf(p.x, s, p.y), 0.f);
  a1 += fmaxf(fmaf(p.z, s, p.w), 0.f);
}

// Dynamic-component visit for ragged row edges (<=6 per row).
__device__ __forceinline__ void visit_dyn(const float4& f4, int j, float tv,
                                          int lane, const float4* ab_s,
                                          float& a0, float& a1) {
  int c = j & 3;
  float comp = (c == 0) ? f4.x : (c == 1) ? f4.y : (c == 2) ? f4.z : f4.w;
  visit(comp, j >> 2, tv, lane, ab_s, a0, a1);
}

// Process HALF of one row. f4 holds the full 256-float row across the wave
// (lane holds cols 4*lane..4*lane+3). Valid cols j in [i0+1, len-1].
// Interior 4-groups [fullLo, fullHi] split at mid: half 0 takes
// [fullLo, mid) plus both ragged edges; half 1 takes [mid, fullHi].
__device__ __forceinline__ void do_row_half(const float4& f4, int i0, int len,
                                            int half, float tv, int lane,
                                            const float4* ab_s,
                                            float& a0, float& a1) {
  const int jlo = i0 + 1, jhi = len - 1;   // inclusive; jhi >= jlo guaranteed
  const int fullLo = (jlo + 3) >> 2;       // first fully-valid 4-group
  const int fullHi = (jhi >= 3) ? ((jhi - 3) >> 2) : -1;  // last fully-valid
  if (fullLo > fullHi) {
    if (half == 0)
      for (int j = jlo; j <= jhi; ++j)
        visit_dyn(f4, j, tv, lane, ab_s, a0, a1);
    return;
  }
  const int mid = (fullLo + fullHi + 1) >> 1;
  if (half == 0) {
    // ragged edges
    for (int j = jlo; j < fullLo * 4; ++j)
      visit_dyn(f4, j, tv, lane, ab_s, a0, a1);
    for (int j = fullHi * 4 + 4; j <= jhi; ++j)
      visit_dyn(f4, j, tv, lane, ab_s, a0, a1);
    // first half of interior groups
#pragma unroll 4
    for (int L = fullLo; L < mid; ++L) {
      visit(f4.x, L, tv, lane, ab_s, a0, a1);
      visit(f4.y, L, tv, lane, ab_s, a0, a1);
      visit(f4.z, L, tv, lane, ab_s, a0, a1);
      visit(f4.w, L, tv, lane, ab_s, a0, a1);
    }
  } else {
    // second half of interior groups
#pragma unroll 4
    for (int L = mid; L <= fullHi; ++L) {
      visit(f4.x, L, tv, lane, ab_s, a0, a1);
      visit(f4.y, L, tv, lane, ab_s, a0, a1);
      visit(f4.z, L, tv, lane, ab_s, a0, a1);
      visit(f4.w, L, tv, lane, ab_s, a0, a1);
    }
  }
}

// ---------------- Kernel B: phi + masked pooling (merged halves) ----------
// grid: (32 chunks, 32 batches) x 1024 threads (16 waves) = 1024 blocks,
// 2 residency rounds -> refill. Wave w handles row (w>>1)*32 + chunk,
// column-half w&1. 66.5KB LDS, 2 blocks/CU, 32 waves/CU.
__global__ __launch_bounds__(1024, 8) void phi_pool(
    const float* __restrict__ dm, const int* __restrict__ lengths,
    const float4* __restrict__ table4, const float* __restrict__ tsort,
    float* __restrict__ pooled) {
  __shared__ float4 ab_s[SEGS * 64];   // 66,560 B
  const int chunk = blockIdx.x;   // 0..31
  const int b     = blockIdx.y;   // batch
  const int tid = threadIdx.x;
  const int lane = tid & 63, w = tid >> 6;   // w: 0..15

  const int len = lengths[b];
  // block-uniform early exit: shortest row in this block is 'chunk'
  if (chunk > len - 2) return;

  for (int i = tid; i < SEGS * 64; i += 1024) ab_s[i] = table4[i];
  __syncthreads();

  const float tv = tsort[lane];      // breakpoint in register, one per lane
  const float* dmb = dm + (size_t)b * (NN * NN);

  const int r = (w >> 1) * 32 + chunk;   // 0..255
  const int half = w & 1;
  if (r > len - 2) return;           // wave-uniform: no work for this row

  const float4 f4 = ((const float4*)(dmb + r * NN))[lane];
  float a0 = 0.f, a1 = 0.f;
  do_row_half(f4, r, len, half, tv, lane, ab_s, a0, a1);

  atomicAdd(&pooled[b * PHI2 + lane], a0);
  atomicAdd(&pooled[b * PHI2 + 64 + lane], a1);
}

// ---------------- Kernel C: rho MLP (no weight staging) ----------------
// grid: 32 blocks (one per batch), 256 threads. Weights read directly from
// global, coalesced; unroll-8 keeps 8 L2-hot loads in flight. Exact order.
__global__ __launch_bounds__(256) void rho_mlp(
    const float* __restrict__ pooled,
    const float* __restrict__ W3, const float* __restrict__ b3,
    const float* __restrict__ W4, const float* __restrict__ b4,
    const float* __restrict__ W5, const float* __restrict__ b5,
    float* __restrict__ out) {
  __shared__ float p_s[128], r1_s[256], r2_s[128];
  const int b = blockIdx.x, tid = threadIdx.x;
  if (tid < 128) p_s[tid] = pooled[b * 128 + tid];
  __syncthreads();
  {
    float acc = b3[tid];
#pragma unroll 8
    for (int k = 0; k < 128; ++k) acc = fmaf(p_s[k], W3[k * 256 + tid], acc);
    r1_s[tid] = fmaxf(acc, 0.f);
  }
  __syncthreads();
  if (tid < 128) {
    float acc = b4[tid];
#pragma unroll 8
    for (int k = 0; k < 256; ++k) acc = fmaf(r1_s[k], W4[k * 128 + tid], acc);
    r2_s[tid] = fmaxf(acc, 0.f);
  }
  __syncthreads();
  if (tid < 64) {
    float acc = b5[tid];
#pragma unroll 8
    for (int k = 0; k < 128; ++k) acc = fmaf(r2_s[k], W5[k * 64 + tid], acc);
    out[b * 64 + tid] = acc;
  }
}

extern "C" void kernel_launch(void* const* d_in, const int* in_sizes, int n_in,
                              void* d_out, int out_size, void* d_ws, size_t ws_size,
                              hipStream_t stream) {
  const float* dm      = (const float*)d_in[0];
  const int*   lengths = (const int*)d_in[1];
  const float* W1 = (const float*)d_in[2];
  const float* b1 = (const float*)d_in[3];
  const float* W2 = (const float*)d_in[4];
  const float* b2 = (const float*)d_in[5];
  const float* W3 = (const float*)d_in[6];
  const float* b3 = (const float*)d_in[7];
  const float* W4 = (const float*)d_in[8];
  const float* b4 = (const float*)d_in[9];
  const float* W5 = (const float*)d_in[10];
  const float* b5 = (const float*)d_in[11];

  float* ws = (float*)d_ws;
  float4* table4 = (float4*)ws;          // 65*64 float4 = 16640 floats
  float* tsort   = ws + 16640;           // 64
  float* pooled  = ws + 16704;           // 32*128 = 4096

  build_tables<<<SEGS, 128, 0, stream>>>(W1, b1, W2, b2, (float2*)table4,
                                         tsort, pooled);
  phi_pool<<<dim3(32, NB), 1024, 0, stream>>>(dm, lengths, table4, tsort,
                                              pooled);
  rho_mlp<<<NB, 256, 0, stream>>>(pooled, W3, b3, W4, b4, W5, b5,
                                  (float*)d_out);
}

// Round 12
// 125.648 us; speedup vs baseline: 1.1001x; 1.1001x over previous
//
#include <hip/hip_runtime.h>

// ScalarDistanceDeepSet: B=32, N=256, pairs P=32640 (upper tri, k=1)
// phi: s -> relu(s*W1+b1)[64] -> relu(.@W2+b2)[128], masked sum over pairs
// rho: pooled[128] -> 256 -> 128 -> 64
//
// g_e(s) is piecewise-linear in s with 64 shared breakpoints. Tables
// alpha/beta[seg][e] make per-(pair,channel) work 1 FMA + 1 max. EXACT.
//
// R18: REVERT to R16 (126.3us session best). R17's half-row split + 2x
// grid regressed (138.2): doubling block count doubles per-block table
// staging (66.5KB L2->LDS prologue each) -- same failure shape as R10's
// parity split. Lever ledger is now complete:
//   pipelining (R12,R14): neutral (TLP already hides LDS latency)
//   finer division (R10,R17): regress (staging multiplies)
//   fusion (R8,R9,R11): regress 3x (backend regalloc collapse)
//   visit-halving @ full occ (R15): WIN  -5.4us
//   de-staging build/rho (R13,R16): WIN -8.1us
// R16 config: merged-half float4 table, 1024-thr phi blocks (2 blk/CU,
// 32 waves/CU), de-staged build_tables + rho_mlp.

#define NB 32
#define NN 256
#define PHI2 128
#define SEGS 65

// ---------------- Kernel A: build tables (no W2 staging) ----------------
// grid: 65 blocks (one per segment), 128 threads (one per output channel e)
// table viewed as float4[seg][l] = (a_l, b_l, a_{l+64}, b_{l+64})
__global__ __launch_bounds__(128) void build_tables(
    const float* __restrict__ W1, const float* __restrict__ b1,
    const float* __restrict__ W2, const float* __restrict__ b2,
    float2* __restrict__ table2,   // float2[(seg*64+l)*2 + h]
    float* __restrict__ tsort, float* __restrict__ pooled) {
  __shared__ float t_s[64], w1_s[64], b1_s[64];
  __shared__ int cat_s[64], rank_s[64];
  const int tid = threadIdx.x;
  const int seg = blockIdx.x;
  if (tid < 64) {
    float w = W1[tid], bb = b1[tid];
    w1_s[tid] = w; b1_s[tid] = bb;
    int cat; float t;
    if (w > 0.f)      { cat = 0; t = -bb / w; }   // active for s > t
    else if (w < 0.f) { cat = 1; t = -bb / w; }   // active for s < t
    else              { cat = (bb > 0.f) ? 2 : 3; t = 0.f; } // always/never
    t_s[tid] = t; cat_s[tid] = cat;
  }
  __syncthreads();
  if (tid < 64) {
    float t = t_s[tid]; int r = 0;
    for (int k = 0; k < 64; ++k) {
      float tk = t_s[k];
      r += (tk < t) || (tk == t && k < tid);   // stable rank
    }
    rank_s[tid] = r;
    if (seg == 0) tsort[r] = t;
  }
  __syncthreads();
  // channel e = tid. seg(s) = #breakpoints strictly < s.
  // W2[j*PHI2+tid]: coalesced across tid, L2-hot, 8 loads in flight.
  float a = 0.f, bsum = b2[tid];
#pragma unroll 8
  for (int j = 0; j < 64; ++j) {
    int cat = cat_s[j], r = rank_s[j];
    bool act = (cat == 0) ? (seg > r) : (cat == 1) ? (seg <= r) : (cat == 2);
    float w2 = W2[j * PHI2 + tid];
    float m = act ? 1.f : 0.f;
    a    = fmaf(m * w1_s[j], w2, a);
    bsum = fmaf(m * b1_s[j], w2, bsum);
  }
  const int h = tid >> 6, l = tid & 63;
  table2[(seg * 64 + l) * 2 + h] = make_float2(a, bsum);
  if (seg == 0) {
    for (int i = tid; i < NB * PHI2; i += 128) pooled[i] = 0.f;
  }
}

__device__ __forceinline__ float bcast(float v, int L) {
  return __int_as_float(__builtin_amdgcn_readlane(__float_as_int(v), L));
}
__device__ __forceinline__ int segof(float tv, float s) {
  return (int)__popcll(__ballot(tv < s));
}

// One (pair) visit covering BOTH channel halves: broadcast s from lane L
// (uniform), segment via ballot over register-held breakpoints, one
// ds_read_b128 -> (a_lo,b_lo,a_hi,b_hi). 1 readlane/ballot per PAIR.
__device__ __forceinline__ void visit(float comp, int L, float tv, int lane,
                                      const float4* ab_s,
                                      float& a0, float& a1) {
  float s = bcast(comp, L);
  float4 p = ab_s[segof(tv, s) * 64 + lane];
  a0 += fmaxf(fmaf(p.x, s, p.y), 0.f);
  a1 += fmaxf(fmaf(p.z, s, p.w), 0.f);
}

// Dynamic-component visit for ragged row edges (<=6 per row).
__device__ __forceinline__ void visit_dyn(const float4& f4, int j, float tv,
                                          int lane, const float4* ab_s,
                                          float& a0, float& a1) {
  int c = j & 3;
  float comp = (c == 0) ? f4.x : (c == 1) ? f4.y : (c == 2) ? f4.z : f4.w;
  visit(comp, j >> 2, tv, lane, ab_s, a0, a1);
}

// Process one row: f4 holds the full 256-float row across the wave
// (lane holds cols 4*lane..4*lane+3). Valid cols j in [i0+1, len-1].
__device__ __forceinline__ void do_row(const float4& f4, int i0, int len,
                                       float tv, int lane,
                                       const float4* ab_s,
                                       float& a0, float& a1) {
  const int jlo = i0 + 1, jhi = len - 1;   // inclusive; jhi >= jlo guaranteed
  const int fullLo = (jlo + 3) >> 2;       // first fully-valid 4-group
  const int fullHi = (jhi >= 3) ? ((jhi - 3) >> 2) : -1;  // last fully-valid
  if (fullLo > fullHi) {
    for (int j = jlo; j <= jhi; ++j) visit_dyn(f4, j, tv, lane, ab_s, a0, a1);
    return;
  }
  // low ragged edge
  for (int j = jlo; j < fullLo * 4; ++j)
    visit_dyn(f4, j, tv, lane, ab_s, a0, a1);
  // interior full groups: uniform L in SGPR, static components
#pragma unroll 4
  for (int L = fullLo; L <= fullHi; ++L) {
    visit(f4.x, L, tv, lane, ab_s, a0, a1);
    visit(f4.y, L, tv, lane, ab_s, a0, a1);
    visit(f4.z, L, tv, lane, ab_s, a0, a1);
    visit(f4.w, L, tv, lane, ab_s, a0, a1);
  }
  // high ragged edge
  for (int j = fullHi * 4 + 4; j <= jhi; ++j)
    visit_dyn(f4, j, tv, lane, ab_s, a0, a1);
}

// ---------------- Kernel B: phi + masked pooling (merged halves) ----------
// grid: (16 chunks, 32 batches) x 1024 threads (16 waves). Wave w handles
// row r = w*16 + chunk (transposed map -> balanced block durations).
// 66.5KB LDS, 2 blocks/CU, 32 waves/CU (full occupancy).
__global__ __launch_bounds__(1024, 8) void phi_pool(
    const float* __restrict__ dm, const int* __restrict__ lengths,
    const float4* __restrict__ table4, const float* __restrict__ tsort,
    float* __restrict__ pooled) {
  __shared__ float4 ab_s[SEGS * 64];   // 66,560 B
  const int chunk = blockIdx.x;   // 0..15
  const int b     = blockIdx.y;   // batch
  const int tid = threadIdx.x;
  const int lane = tid & 63, w = tid >> 6;   // w: 0..15

  const int len = lengths[b];
  // block-uniform early exit: shortest row in this block is 'chunk'
  if (chunk > len - 2) return;

  for (int i = tid; i < SEGS * 64; i += 1024) ab_s[i] = table4[i];
  __syncthreads();

  const float tv = tsort[lane];      // breakpoint in register, one per lane
  const float* dmb = dm + (size_t)b * (NN * NN);

  const int r = w * 16 + chunk;      // 0..255
  if (r > len - 2) return;           // wave-uniform: no work for this row

  const float4 f4 = ((const float4*)(dmb + r * NN))[lane];
  float a0 = 0.f, a1 = 0.f;
  do_row(f4, r, len, tv, lane, ab_s, a0, a1);

  atomicAdd(&pooled[b * PHI2 + lane], a0);
  atomicAdd(&pooled[b * PHI2 + 64 + lane], a1);
}

// ---------------- Kernel C: rho MLP (no weight staging) ----------------
// grid: 32 blocks (one per batch), 256 threads. Weights read directly from
// global, coalesced; unroll-8 keeps 8 L2-hot loads in flight. Exact order.
__global__ __launch_bounds__(256) void rho_mlp(
    const float* __restrict__ pooled,
    const float* __restrict__ W3, const float* __restrict__ b3,
    const float* __restrict__ W4, const float* __restrict__ b4,
    const float* __restrict__ W5, const float* __restrict__ b5,
    float* __restrict__ out) {
  __shared__ float p_s[128], r1_s[256], r2_s[128];
  const int b = blockIdx.x, tid = threadIdx.x;
  if (tid < 128) p_s[tid] = pooled[b * 128 + tid];
  __syncthreads();
  {
    float acc = b3[tid];
#pragma unroll 8
    for (int k = 0; k < 128; ++k) acc = fmaf(p_s[k], W3[k * 256 + tid], acc);
    r1_s[tid] = fmaxf(acc, 0.f);
  }
  __syncthreads();
  if (tid < 128) {
    float acc = b4[tid];
#pragma unroll 8
    for (int k = 0; k < 256; ++k) acc = fmaf(r1_s[k], W4[k * 128 + tid], acc);
    r2_s[tid] = fmaxf(acc, 0.f);
  }
  __syncthreads();
  if (tid < 64) {
    float acc = b5[tid];
#pragma unroll 8
    for (int k = 0; k < 128; ++k) acc = fmaf(r2_s[k], W5[k * 64 + tid], acc);
    out[b * 64 + tid] = acc;
  }
}

extern "C" void kernel_launch(void* const* d_in, const int* in_sizes, int n_in,
                              void* d_out, int out_size, void* d_ws, size_t ws_size,
                              hipStream_t stream) {
  const float* dm      = (const float*)d_in[0];
  const int*   lengths = (const int*)d_in[1];
  const float* W1 = (const float*)d_in[2];
  const float* b1 = (const float*)d_in[3];
  const float* W2 = (const float*)d_in[4];
  const float* b2 = (const float*)d_in[5];
  const float* W3 = (const float*)d_in[6];
  const float* b3 = (const float*)d_in[7];
  const float* W4 = (const float*)d_in[8];
  const float* b4 = (const float*)d_in[9];
  const float* W5 = (const float*)d_in[10];
  const float* b5 = (const float*)d_in[11];

  float* ws = (float*)d_ws;
  float4* table4 = (float4*)ws;          // 65*64 float4 = 16640 floats
  float* tsort   = ws + 16640;           // 64
  float* pooled  = ws + 16704;           // 32*128 = 4096

  build_tables<<<SEGS, 128, 0, stream>>>(W1, b1, W2, b2, (float2*)table4,
                                         tsort, pooled);
  phi_pool<<<dim3(16, NB), 1024, 0, stream>>>(dm, lengths, table4, tsort,
                                              pooled);
  rho_mlp<<<NB, 256, 0, stream>>>(pooled, W3, b3, W4, b4, W5, b5,
                                  (float*)d_out);
}